// Round 14
// baseline (328.265 us; speedup 1.0000x reference)
//
#include <hip/hip_runtime.h>
#include <math.h>

typedef unsigned long long u64;

// ---------------------------------------------------------------------------
// Kernel 1: KNN (bit-exact vs np/fp32 reference) + fused 3-scale surface conv.
// (identical to round 10)
// ---------------------------------------------------------------------------
__global__ __launch_bounds__(256) void knnsurf_kernel(
    const float* __restrict__ verts,
    int* __restrict__ idx_out, float4* __restrict__ nd_out,
    const float* __restrict__ dl, const float* __restrict__ dm,
    const float* __restrict__ dg,
    float* __restrict__ raw_l, float* __restrict__ raw_m, float* __restrict__ raw_g)
{
    __shared__ float4 vps[1024];                    // x,y,z,sq  (16 KB)
    __shared__ __align__(16) u64 cand[4][208];      // 6.7 KB
    const int tid = threadIdx.x;
    const int row0 = blockIdx.x * 4;
    const int b = row0 >> 10;
    const float* vb = verts + b * 3072;

    for (int n = tid; n < 1024; n += 256) {
        float x = vb[3 * n], y = vb[3 * n + 1], z = vb[3 * n + 2];
        float s = __fadd_rn(__fadd_rn(__fmul_rn(x, x), __fmul_rn(y, y)),
                            __fmul_rn(z, z));
        vps[n] = make_float4(x, y, z, s);
    }
    __syncthreads();

    const int w = tid >> 6, lane = tid & 63;
    const int row = row0 + w;
    const int n_i = row & 1023;
    const float4 pi = vps[n_i];
    const float xi = pi.x, yi = pi.y, zi = pi.z, sqi = pi.w;

    u64 K[16];
    u64 m1 = ~0ULL, m2 = ~0ULL;
#pragma unroll
    for (int t = 0; t < 16; ++t) {
        int j = t * 64 + lane;
        float4 p = vps[j];
        float dot = __fadd_rn(__fadd_rn(__fmul_rn(xi, p.x),
                                        __fmul_rn(yi, p.y)),
                              __fmul_rn(zi, p.z));
        float d = __fsub_rn(__fadd_rn(sqi, p.w), __fmul_rn(2.0f, dot));
        d = __fadd_rn(d, 0.0f);
        unsigned u = __float_as_uint(d);
        unsigned m = (u & 0x80000000u) ? ~u : (u | 0x80000000u);
        u64 k = ((u64)m << 10) | (unsigned)j;
        K[t] = k;
        bool lt1 = k < m1;
        u64 nm2 = lt1 ? m1 : ((k < m2) ? k : m2);
        m1 = lt1 ? k : m1;
        m2 = nm2;
    }

    u64 tmax = m2, tmin = m1;
#pragma unroll
    for (int off = 1; off < 64; off <<= 1) {
        u64 a = __shfl_xor(tmax, off); if (a > tmax) tmax = a;
        u64 c = __shfl_xor(tmin, off); if (c < tmin) tmin = c;
    }

    u64 T = tmax;
    int chi;
    {
        int c = 0;
#pragma unroll
        for (int t = 0; t < 16; ++t) c += (K[t] < T) ? 1 : 0;
#pragma unroll
        for (int off = 1; off < 64; off <<= 1) c += __shfl_xor(c, off);
        chi = c;
    }
    u64 lo = tmin, hi = T;
    while (chi > 192) {
        u64 mid = (lo + hi) >> 1;
        int c = 0;
#pragma unroll
        for (int t = 0; t < 16; ++t) c += (K[t] < mid) ? 1 : 0;
#pragma unroll
        for (int off = 1; off < 64; off <<= 1) c += __shfl_xor(c, off);
        if (c >= 101) { hi = mid; chi = c; } else lo = mid;
    }
    T = hi;
    const int n = chi;

    int myc_n = 0;
#pragma unroll
    for (int t = 0; t < 16; ++t) myc_n += (K[t] < T) ? 1 : 0;
    int sc = myc_n;
#pragma unroll
    for (int off = 1; off < 64; off <<= 1) {
        int v = __shfl_up(sc, off);
        if (lane >= off) sc += v;
    }
    int pos = sc - myc_n;
#pragma unroll
    for (int t = 0; t < 16; ++t) {
        if (K[t] < T) cand[w][pos++] = K[t];
    }
    if (lane == 0) cand[w][n] = ~0ULL;
    __syncthreads();

    u64 myc[3]; int rk[3];
#pragma unroll
    for (int q = 0; q < 3; ++q) {
        int i = lane + q * 64;
        myc[q] = (i < n) ? cand[w][i] : ~0ULL;
        rk[q] = 0;
    }
    {
        const ulonglong2* c2 = (const ulonglong2*)&cand[w][0];
        const int half = (n + 1) >> 1;
        for (int jj = 0; jj < half; ++jj) {
            ulonglong2 kk = c2[jj];
#pragma unroll
            for (int q = 0; q < 3; ++q) {
                rk[q] += (kk.x < myc[q]) ? 1 : 0;
                rk[q] += (kk.y < myc[q]) ? 1 : 0;
            }
        }
    }

    const int rowbase = row & ~1023;
    float4* nd4w = (float4*)&cand[w][0];
#pragma unroll
    for (int q = 0; q < 3; ++q) {
        int i = lane + q * 64;
        if (i < n) {
            int r = rk[q];
            if (r >= 1 && r <= 100) {
                int slot = r - 1;
                unsigned j = (unsigned)(myc[q] & 1023u);
                idx_out[row * 100 + slot] = rowbase + (int)j;
                float4 pj = vps[j];
                float dx = pj.x - xi, dy = pj.y - yi, dz = pj.z - zi;
                float nrm = sqrtf(__fadd_rn(__fadd_rn(__fmul_rn(dx, dx),
                                                      __fmul_rn(dy, dy)),
                                            __fmul_rn(dz, dz)));
                float inv = 1.0f / fmaxf(nrm, 1e-12f);
                float4 nv = make_float4(dx * inv, dy * inv, dz * inv, 0.0f);
                nd_out[row * 100 + slot] = nv;
                nd4w[slot] = nv;
            }
        }
    }
    __syncthreads();

    const int d = tid & 127;
    float lx = dl[d], ly = dl[128 + d], lz = dl[256 + d];
    float li = 1.0f / fmaxf(sqrtf((lx * lx + ly * ly) + lz * lz), 1e-12f);
    lx *= li; ly *= li; lz *= li;
    float mx = dm[d], my = dm[128 + d], mz = dm[256 + d];
    float mi = 1.0f / fmaxf(sqrtf((mx * mx + my * my) + mz * mz), 1e-12f);
    mx *= mi; my *= mi; mz *= mi;
    float gx = dg[d], gy = dg[128 + d], gz = dg[256 + d];
    float gi = 1.0f / fmaxf(sqrtf((gx * gx + gy * gy) + gz * gz), 1e-12f);
    gx *= gi; gy *= gi; gz *= gi;

#pragma unroll
    for (int p = 0; p < 2; ++p) {
        int rr = (tid >> 7) + 2 * p;
        const float4* ns = (const float4*)&cand[rr][0];
        float ml = -1e30f, mm = -1e30f, mg = -1e30f;
        int k = 0;
        for (; k < 5; ++k) {
            float4 v = ns[k];
            ml = fmaxf(ml, (v.x * lx + v.y * ly) + v.z * lz);
            mm = fmaxf(mm, (v.x * mx + v.y * my) + v.z * mz);
            mg = fmaxf(mg, (v.x * gx + v.y * gy) + v.z * gz);
        }
        for (; k < 20; ++k) {
            float4 v = ns[k];
            mm = fmaxf(mm, (v.x * mx + v.y * my) + v.z * mz);
            mg = fmaxf(mg, (v.x * gx + v.y * gy) + v.z * gz);
        }
        for (; k < 100; ++k) {
            float4 v = ns[k];
            mg = fmaxf(mg, (v.x * gx + v.y * gy) + v.z * gz);
        }
        int orow = row0 + rr;
        raw_l[orow * 128 + d] = fmaxf(ml, 0.0f);
        raw_m[orow * 128 + d] = fmaxf(mm, 0.0f);
        raw_g[orow * 128 + d] = fmaxf(mg, 0.0f);
    }
}

// ---------------------------------------------------------------------------
// Kernel 2: BN partial sums: 32 blocks per tensor (fp64, deterministic).
// ---------------------------------------------------------------------------
__global__ __launch_bounds__(256) void bnsum_kernel(
    const float* s0, double* p0,
    const float* s1, double* p1,
    const float* s2, double* p2)
{
    const int t = blockIdx.x >> 5;
    const int blk = blockIdx.x & 31;
    const float* src = (t == 0) ? s0 : (t == 1) ? s1 : s2;
    double* p = (t == 0) ? p0 : (t == 1) ? p1 : p2;
    const int tid = threadIdx.x;
    const int c = tid & 127, seg = tid >> 7;
    const float* q = src + ((size_t)blk * 128 + seg * 64) * 128 + c;
    double s = 0.0, ss = 0.0;
    for (int r = 0; r < 64; ++r) { float v = q[r * 128]; s += v; ss += (double)v * v; }
    __shared__ double Ls[2][128], Lq[2][128];
    Ls[seg][c] = s; Lq[seg][c] = ss;
    __syncthreads();
    if (tid < 128) {
        p[blk * 256 + c]       = Ls[0][c] + Ls[1][c];
        p[blk * 256 + 128 + c] = Lq[0][c] + Lq[1][c];
    }
}

// st from partials: a = g/sqrt(var+eps), b2 = e - m*a (fp64, deterministic)
__device__ __forceinline__ void compute_st(const double* __restrict__ p,
                                           const float* __restrict__ g,
                                           const float* __restrict__ e,
                                           float* stA, float* stB,
                                           int tid, int nthreads)
{
    for (int c = tid; c < 128; c += nthreads) {
        double S = 0.0, Q = 0.0;
#pragma unroll
        for (int bb = 0; bb < 32; ++bb) { S += p[bb * 256 + c]; Q += p[bb * 256 + 128 + c]; }
        double m = S * (1.0 / 4096.0);
        double var = Q * (1.0 / 4096.0) - m * m;
        double a = (double)g[c] / sqrt(var + 1e-5);
        stA[c] = (float)a;
        stB[c] = (float)((double)e[c] - m * a);
    }
}

// ---------------------------------------------------------------------------
// Kernel 3: dual-job GEMM (CIN=128). 256-thread block, 8 staged rows.
// Wave-pair mapping: waves{0,1}=rows 0-3 cols [0:128)/[128:256);
// waves{2,3}=rows 4-7. Lane owns 2 cols (colb+lane, colb+64+lane).
// Per c-quad/wave: 4 LDS b128 feed 32 FMA (VALU-bound); W read once/block.
// ---------------------------------------------------------------------------
__global__ __launch_bounds__(256) void gemm2_kernel(
    const float* __restrict__ Aa, const double* __restrict__ pa,
    const float* __restrict__ ga, const float* __restrict__ ea,
    const float* __restrict__ Wa, const float* __restrict__ ba, float* __restrict__ outa,
    const float* __restrict__ Ab, const double* __restrict__ pb,
    const float* __restrict__ gb, const float* __restrict__ eb,
    const float* __restrict__ Wb, const float* __restrict__ bb, float* __restrict__ outb)
{
    const int job = blockIdx.y;
    const float* A = job ? Ab : Aa;  const double* p = job ? pb : pa;
    const float* g = job ? gb : ga;  const float* e = job ? eb : ea;
    const float* W = job ? Wb : Wa;  const float* bias = job ? bb : ba;
    float* out = job ? outb : outa;

    __shared__ float stA[128], stB[128];
    __shared__ float As[8 * 128];
    const int o = threadIdx.x;
    const int r0 = blockIdx.x * 8;

    compute_st(p, g, e, stA, stB, o, 256);
    __syncthreads();

    for (int t = o; t < 8 * 128; t += 256) {
        int r = t >> 7, c = t & 127;
        As[t] = fmaxf(fmaf(stA[c], A[(r0 + r) * 128 + c], stB[c]), 0.0f);
    }
    __syncthreads();

    const int wv = o >> 6, lane = o & 63;
    const int colb = (wv & 1) * 128;
    const int col0 = colb + lane, col1 = colb + 64 + lane;
    const int rb = (wv >> 1) * 4;                 // rows rb..rb+3 of the tile

    float acc0[4], acc1[4];
    const float bz0 = bias[col0], bz1 = bias[col1];
#pragma unroll
    for (int r = 0; r < 4; ++r) { acc0[r] = bz0; acc1[r] = bz1; }

    for (int c = 0; c < 128; c += 4) {
        const float* Wc = W + (size_t)c * 256;
        float w00 = Wc[col0],       w10 = Wc[col1];
        float w01 = Wc[256 + col0], w11 = Wc[256 + col1];
        float w02 = Wc[512 + col0], w12 = Wc[512 + col1];
        float w03 = Wc[768 + col0], w13 = Wc[768 + col1];
#pragma unroll
        for (int r = 0; r < 4; ++r) {
            const float4 av = *(const float4*)&As[(rb + r) * 128 + c]; // broadcast
            acc0[r] += av.x * w00 + av.y * w01 + av.z * w02 + av.w * w03;
            acc1[r] += av.x * w10 + av.y * w11 + av.z * w12 + av.w * w13;
        }
    }
#pragma unroll
    for (int r = 0; r < 4; ++r) {
        out[(size_t)(r0 + rb + r) * 256 + col0] = acc0[r];
        out[(size_t)(r0 + rb + r) * 256 + col1] = acc1[r];
    }
}

// ---------------------------------------------------------------------------
// Kernel 4: conv-layer apply (unchanged).
// ---------------------------------------------------------------------------
__global__ __launch_bounds__(128) void layer_kernel(
    const float4* __restrict__ nd, const int* __restrict__ idxbuf,
    const float* dir0, const float* fo0, float* out0, int K0,
    const float* dir1, const float* fo1, float* out1, int K1)
{
    const int job = blockIdx.y;
    const float* dirs = job ? dir1 : dir0;
    const float* fo = job ? fo1 : fo0;
    float* out = job ? out1 : out0;
    const int K = job ? K1 : K0;

    const int d = threadIdx.x;
    const int row = blockIdx.x;

    float dx = dirs[d], dy = dirs[128 + d], dz = dirs[256 + d];
    float di = 1.0f / fmaxf(sqrtf((dx * dx + dy * dy) + dz * dz), 1e-12f);
    dx *= di; dy *= di; dz *= di;

    const float4* ns = nd + (size_t)row * 100;
    const int* ib = idxbuf + (size_t)row * 100;

    float acc = -1e30f;
    for (int k = 0; k < K; ++k) {
        float4 v = ns[k];
        int ix = ib[k];
        float th = fmaxf((v.x * dx + v.y * dy) + v.z * dz, 0.0f);
        float fs = fo[ix * 256 + 128 + d];
        acc = fmaxf(acc, th * fs);
    }
    out[row * 128 + d] = fo[row * 256 + d] + acc;
}

// ---------------------------------------------------------------------------
// Kernel 5: final GEMM (CIN=384). Same wave-pair mapping as gemm2; bn_relu
// fused into staging; final relu; fp32 out.
// ---------------------------------------------------------------------------
__global__ __launch_bounds__(256) void gemmf_kernel(
    const float* __restrict__ A0t, const double* __restrict__ p0,
    const float* __restrict__ g0, const float* __restrict__ e0,
    const float* __restrict__ A1t, const double* __restrict__ p1,
    const float* __restrict__ g1, const float* __restrict__ e1,
    const float* __restrict__ A2t, const double* __restrict__ p2,
    const float* __restrict__ g2, const float* __restrict__ e2,
    const float* __restrict__ W, const float* __restrict__ bias, float* __restrict__ out)
{
    __shared__ float stA[384], stB[384];
    __shared__ float As[8 * 384];
    const int o = threadIdx.x;
    const int r0 = blockIdx.x * 8;

    compute_st(p0, g0, e0, stA,       stB,       o, 256);
    compute_st(p1, g1, e1, stA + 128, stB + 128, o, 256);
    compute_st(p2, g2, e2, stA + 256, stB + 256, o, 256);
    __syncthreads();

    for (int t = o; t < 8 * 384; t += 256) {
        int r = t / 384, c = t - r * 384;
        int seg = c >> 7, cc = c & 127;
        const float* A = (seg == 0) ? A0t : (seg == 1) ? A1t : A2t;
        As[t] = fmaxf(fmaf(stA[c], A[(r0 + r) * 128 + cc], stB[c]), 0.0f);
    }
    __syncthreads();

    const int wv = o >> 6, lane = o & 63;
    const int colb = (wv & 1) * 128;
    const int col0 = colb + lane, col1 = colb + 64 + lane;
    const int rb = (wv >> 1) * 4;

    float acc0[4], acc1[4];
    const float bz0 = bias[col0], bz1 = bias[col1];
#pragma unroll
    for (int r = 0; r < 4; ++r) { acc0[r] = bz0; acc1[r] = bz1; }

    for (int c = 0; c < 384; c += 4) {
        const float* Wc = W + (size_t)c * 256;
        float w00 = Wc[col0],       w10 = Wc[col1];
        float w01 = Wc[256 + col0], w11 = Wc[256 + col1];
        float w02 = Wc[512 + col0], w12 = Wc[512 + col1];
        float w03 = Wc[768 + col0], w13 = Wc[768 + col1];
#pragma unroll
        for (int r = 0; r < 4; ++r) {
            const float4 av = *(const float4*)&As[(rb + r) * 384 + c]; // broadcast
            acc0[r] += av.x * w00 + av.y * w01 + av.z * w02 + av.w * w03;
            acc1[r] += av.x * w10 + av.y * w11 + av.z * w12 + av.w * w13;
        }
    }
#pragma unroll
    for (int r = 0; r < 4; ++r) {
        out[(size_t)(r0 + rb + r) * 256 + col0] = fmaxf(acc0[r], 0.0f);
        out[(size_t)(r0 + rb + r) * 256 + col1] = fmaxf(acc1[r], 0.0f);
    }
}

// ---------------------------------------------------------------------------
extern "C" void kernel_launch(void* const* d_in, const int* in_sizes, int n_in,
                              void* d_out, int out_size, void* d_ws, size_t ws_size,
                              hipStream_t stream)
{
    (void)in_sizes; (void)n_in; (void)out_size; (void)ws_size;

    const float* verts   = (const float*)d_in[0];
    const float* dirs_l  = (const float*)d_in[1];
    const float* dirs_m0 = (const float*)d_in[2];
    const float* W_m1    = (const float*)d_in[3];
    const float* b_m1    = (const float*)d_in[4];
    const float* dirs_m1 = (const float*)d_in[5];
    const float* dirs_g0 = (const float*)d_in[6];
    const float* W_g1    = (const float*)d_in[7];
    const float* b_g1    = (const float*)d_in[8];
    const float* dirs_g1 = (const float*)d_in[9];
    const float* W_g2    = (const float*)d_in[10];
    const float* b_g2    = (const float*)d_in[11];
    const float* dirs_g2 = (const float*)d_in[12];
    const float* g_l  = (const float*)d_in[13]; const float* be_l  = (const float*)d_in[14];
    const float* g_m0 = (const float*)d_in[15]; const float* be_m0 = (const float*)d_in[16];
    const float* g_m1 = (const float*)d_in[17]; const float* be_m1 = (const float*)d_in[18];
    const float* g_g0 = (const float*)d_in[19]; const float* be_g0 = (const float*)d_in[20];
    const float* g_g1 = (const float*)d_in[21]; const float* be_g1 = (const float*)d_in[22];
    const float* g_g2 = (const float*)d_in[23]; const float* be_g2 = (const float*)d_in[24];
    const float* W_down = (const float*)d_in[25];
    const float* b_down = (const float*)d_in[26];

    char* ws = (char*)d_ws;
    const size_t MB = 1 << 20;
    int*    idx100 = (int*)   (ws + 0);               // 1.64 MB
    double* p_l    = (double*)(ws + 0x1A0000);        // 6 x 64 KB fp64 partials
    double* p_m0   = p_l  + 8192;
    double* p_m1   = p_m0 + 8192;
    double* p_g0   = p_m1 + 8192;
    double* p_g1   = p_g0 + 8192;
    double* p_g2   = p_g1 + 8192;
    float4* nd100  = (float4*)(ws + 2 * MB);          // 6.55 MB (stride-4)
    float* raw_l  = (float*)(ws +  9 * MB);           // 2 MB each
    float* raw_m0 = (float*)(ws + 11 * MB);
    float* raw_g0 = (float*)(ws + 13 * MB);
    float* raw_m1 = (float*)(ws + 15 * MB);
    float* raw_g1 = (float*)(ws + 17 * MB);
    float* raw_g2 = (float*)(ws + 19 * MB);
    float* fo_m   = (float*)(ws + 21 * MB);           // 4 MB each
    float* fo_g   = (float*)(ws + 25 * MB);
    float* fo_g2  = (float*)(ws + 29 * MB);

    // L1. KNN + nd + fused surface convs
    knnsurf_kernel<<<1024, 256, 0, stream>>>(verts, idx100, nd100,
                                             dirs_l, dirs_m0, dirs_g0,
                                             raw_l, raw_m0, raw_g0);
    // L2. BN partials for l, m0, g0
    bnsum_kernel<<<96, 256, 0, stream>>>(raw_l, p_l, raw_m0, p_m0, raw_g0, p_g0);
    // L3. fo_m = bn_relu(raw_m0) @ W_m1 ; fo_g = bn_relu(raw_g0) @ W_g1
    gemm2_kernel<<<dim3(512, 2), 256, 0, stream>>>(
        raw_m0, p_m0, g_m0, be_m0, W_m1, b_m1, fo_m,
        raw_g0, p_g0, g_g0, be_g0, W_g1, b_g1, fo_g);
    // L4. conv-layer apply (m1: K=20, g1: K=100)
    layer_kernel<<<dim3(4096, 2), 128, 0, stream>>>(nd100, idx100,
                                                    dirs_m1, fo_m, raw_m1, 20,
                                                    dirs_g1, fo_g, raw_g1, 100);
    // L5. BN partials for m1, g1
    bnsum_kernel<<<64, 256, 0, stream>>>(raw_m1, p_m1, raw_g1, p_g1, raw_g1, p_g1);
    // L6. fo_g2 = bn_relu(raw_g1) @ W_g2
    gemm2_kernel<<<dim3(512, 1), 256, 0, stream>>>(
        raw_g1, p_g1, g_g1, be_g1, W_g2, b_g2, fo_g2,
        raw_g1, p_g1, g_g1, be_g1, W_g2, b_g2, fo_g2);
    // L7. conv-layer apply (g2: K=100)
    layer_kernel<<<dim3(4096, 1), 128, 0, stream>>>(nd100, idx100,
                                                    dirs_g2, fo_g2, raw_g2, 100,
                                                    dirs_g2, fo_g2, raw_g2, 100);
    // L8. BN partials for g2
    bnsum_kernel<<<32, 256, 0, stream>>>(raw_g2, p_g2, raw_g2, p_g2, raw_g2, p_g2);
    // L9. final: relu(concat(bn_relu each) @ W_down + b_down) -> fp32 out
    gemmf_kernel<<<512, 256, 0, stream>>>(raw_l, p_l, g_l, be_l,
                                          raw_m1, p_m1, g_m1, be_m1,
                                          raw_g2, p_g2, g_g2, be_g2,
                                          W_down, b_down, (float*)d_out);
}

// Round 15
// 275.444 us; speedup vs baseline: 1.1918x; 1.1918x over previous
//
#include <hip/hip_runtime.h>
#include <math.h>

typedef unsigned long long u64;

// ---------------------------------------------------------------------------
// Kernel 1: KNN (bit-exact vs np/fp32 reference) + fused 3-scale surface conv.
// (identical to round 10 — session-best structure)
// ---------------------------------------------------------------------------
__global__ __launch_bounds__(256) void knnsurf_kernel(
    const float* __restrict__ verts,
    int* __restrict__ idx_out, float4* __restrict__ nd_out,
    const float* __restrict__ dl, const float* __restrict__ dm,
    const float* __restrict__ dg,
    float* __restrict__ raw_l, float* __restrict__ raw_m, float* __restrict__ raw_g)
{
    __shared__ float4 vps[1024];                    // x,y,z,sq  (16 KB)
    __shared__ __align__(16) u64 cand[4][208];      // 6.7 KB
    const int tid = threadIdx.x;
    const int row0 = blockIdx.x * 4;
    const int b = row0 >> 10;
    const float* vb = verts + b * 3072;

    for (int n = tid; n < 1024; n += 256) {
        float x = vb[3 * n], y = vb[3 * n + 1], z = vb[3 * n + 2];
        float s = __fadd_rn(__fadd_rn(__fmul_rn(x, x), __fmul_rn(y, y)),
                            __fmul_rn(z, z));
        vps[n] = make_float4(x, y, z, s);
    }
    __syncthreads();

    const int w = tid >> 6, lane = tid & 63;
    const int row = row0 + w;
    const int n_i = row & 1023;
    const float4 pi = vps[n_i];
    const float xi = pi.x, yi = pi.y, zi = pi.z, sqi = pi.w;

    u64 K[16];
    u64 m1 = ~0ULL, m2 = ~0ULL;
#pragma unroll
    for (int t = 0; t < 16; ++t) {
        int j = t * 64 + lane;
        float4 p = vps[j];
        float dot = __fadd_rn(__fadd_rn(__fmul_rn(xi, p.x),
                                        __fmul_rn(yi, p.y)),
                              __fmul_rn(zi, p.z));
        float d = __fsub_rn(__fadd_rn(sqi, p.w), __fmul_rn(2.0f, dot));
        d = __fadd_rn(d, 0.0f);
        unsigned u = __float_as_uint(d);
        unsigned m = (u & 0x80000000u) ? ~u : (u | 0x80000000u);
        u64 k = ((u64)m << 10) | (unsigned)j;
        K[t] = k;
        bool lt1 = k < m1;
        u64 nm2 = lt1 ? m1 : ((k < m2) ? k : m2);
        m1 = lt1 ? k : m1;
        m2 = nm2;
    }

    u64 tmax = m2, tmin = m1;
#pragma unroll
    for (int off = 1; off < 64; off <<= 1) {
        u64 a = __shfl_xor(tmax, off); if (a > tmax) tmax = a;
        u64 c = __shfl_xor(tmin, off); if (c < tmin) tmin = c;
    }

    u64 T = tmax;
    int chi;
    {
        int c = 0;
#pragma unroll
        for (int t = 0; t < 16; ++t) c += (K[t] < T) ? 1 : 0;
#pragma unroll
        for (int off = 1; off < 64; off <<= 1) c += __shfl_xor(c, off);
        chi = c;
    }
    u64 lo = tmin, hi = T;
    while (chi > 192) {
        u64 mid = (lo + hi) >> 1;
        int c = 0;
#pragma unroll
        for (int t = 0; t < 16; ++t) c += (K[t] < mid) ? 1 : 0;
#pragma unroll
        for (int off = 1; off < 64; off <<= 1) c += __shfl_xor(c, off);
        if (c >= 101) { hi = mid; chi = c; } else lo = mid;
    }
    T = hi;
    const int n = chi;

    int myc_n = 0;
#pragma unroll
    for (int t = 0; t < 16; ++t) myc_n += (K[t] < T) ? 1 : 0;
    int sc = myc_n;
#pragma unroll
    for (int off = 1; off < 64; off <<= 1) {
        int v = __shfl_up(sc, off);
        if (lane >= off) sc += v;
    }
    int pos = sc - myc_n;
#pragma unroll
    for (int t = 0; t < 16; ++t) {
        if (K[t] < T) cand[w][pos++] = K[t];
    }
    if (lane == 0) cand[w][n] = ~0ULL;
    __syncthreads();

    u64 myc[3]; int rk[3];
#pragma unroll
    for (int q = 0; q < 3; ++q) {
        int i = lane + q * 64;
        myc[q] = (i < n) ? cand[w][i] : ~0ULL;
        rk[q] = 0;
    }
    {
        const ulonglong2* c2 = (const ulonglong2*)&cand[w][0];
        const int half = (n + 1) >> 1;
        for (int jj = 0; jj < half; ++jj) {
            ulonglong2 kk = c2[jj];
#pragma unroll
            for (int q = 0; q < 3; ++q) {
                rk[q] += (kk.x < myc[q]) ? 1 : 0;
                rk[q] += (kk.y < myc[q]) ? 1 : 0;
            }
        }
    }

    const int rowbase = row & ~1023;
    float4* nd4w = (float4*)&cand[w][0];
#pragma unroll
    for (int q = 0; q < 3; ++q) {
        int i = lane + q * 64;
        if (i < n) {
            int r = rk[q];
            if (r >= 1 && r <= 100) {
                int slot = r - 1;
                unsigned j = (unsigned)(myc[q] & 1023u);
                idx_out[row * 100 + slot] = rowbase + (int)j;
                float4 pj = vps[j];
                float dx = pj.x - xi, dy = pj.y - yi, dz = pj.z - zi;
                float nrm = sqrtf(__fadd_rn(__fadd_rn(__fmul_rn(dx, dx),
                                                      __fmul_rn(dy, dy)),
                                            __fmul_rn(dz, dz)));
                float inv = 1.0f / fmaxf(nrm, 1e-12f);
                float4 nv = make_float4(dx * inv, dy * inv, dz * inv, 0.0f);
                nd_out[row * 100 + slot] = nv;
                nd4w[slot] = nv;
            }
        }
    }
    __syncthreads();

    const int d = tid & 127;
    float lx = dl[d], ly = dl[128 + d], lz = dl[256 + d];
    float li = 1.0f / fmaxf(sqrtf((lx * lx + ly * ly) + lz * lz), 1e-12f);
    lx *= li; ly *= li; lz *= li;
    float mx = dm[d], my = dm[128 + d], mz = dm[256 + d];
    float mi = 1.0f / fmaxf(sqrtf((mx * mx + my * my) + mz * mz), 1e-12f);
    mx *= mi; my *= mi; mz *= mi;
    float gx = dg[d], gy = dg[128 + d], gz = dg[256 + d];
    float gi = 1.0f / fmaxf(sqrtf((gx * gx + gy * gy) + gz * gz), 1e-12f);
    gx *= gi; gy *= gi; gz *= gi;

#pragma unroll
    for (int p = 0; p < 2; ++p) {
        int rr = (tid >> 7) + 2 * p;
        const float4* ns = (const float4*)&cand[rr][0];
        float ml = -1e30f, mm = -1e30f, mg = -1e30f;
        int k = 0;
        for (; k < 5; ++k) {
            float4 v = ns[k];
            ml = fmaxf(ml, (v.x * lx + v.y * ly) + v.z * lz);
            mm = fmaxf(mm, (v.x * mx + v.y * my) + v.z * mz);
            mg = fmaxf(mg, (v.x * gx + v.y * gy) + v.z * gz);
        }
        for (; k < 20; ++k) {
            float4 v = ns[k];
            mm = fmaxf(mm, (v.x * mx + v.y * my) + v.z * mz);
            mg = fmaxf(mg, (v.x * gx + v.y * gy) + v.z * gz);
        }
        for (; k < 100; ++k) {
            float4 v = ns[k];
            mg = fmaxf(mg, (v.x * gx + v.y * gy) + v.z * gz);
        }
        int orow = row0 + rr;
        raw_l[orow * 128 + d] = fmaxf(ml, 0.0f);
        raw_m[orow * 128 + d] = fmaxf(mm, 0.0f);
        raw_g[orow * 128 + d] = fmaxf(mg, 0.0f);
    }
}

// ---------------------------------------------------------------------------
// Kernel 2: BN partial sums: 32 blocks per tensor (fp64, deterministic).
// ---------------------------------------------------------------------------
__global__ __launch_bounds__(256) void bnsum_kernel(
    const float* s0, double* p0,
    const float* s1, double* p1,
    const float* s2, double* p2)
{
    const int t = blockIdx.x >> 5;
    const int blk = blockIdx.x & 31;
    const float* src = (t == 0) ? s0 : (t == 1) ? s1 : s2;
    double* p = (t == 0) ? p0 : (t == 1) ? p1 : p2;
    const int tid = threadIdx.x;
    const int c = tid & 127, seg = tid >> 7;
    const float* q = src + ((size_t)blk * 128 + seg * 64) * 128 + c;
    double s = 0.0, ss = 0.0;
    for (int r = 0; r < 64; ++r) { float v = q[r * 128]; s += v; ss += (double)v * v; }
    __shared__ double Ls[2][128], Lq[2][128];
    Ls[seg][c] = s; Lq[seg][c] = ss;
    __syncthreads();
    if (tid < 128) {
        p[blk * 256 + c]       = Ls[0][c] + Ls[1][c];
        p[blk * 256 + 128 + c] = Lq[0][c] + Lq[1][c];
    }
}

// st from partials: a = g/sqrt(var+eps), b2 = e - m*a (fp64, deterministic)
__device__ __forceinline__ void compute_st(const double* __restrict__ p,
                                           const float* __restrict__ g,
                                           const float* __restrict__ e,
                                           float* stA, float* stB,
                                           int tid, int nthreads)
{
    for (int c = tid; c < 128; c += nthreads) {
        double S = 0.0, Q = 0.0;
#pragma unroll
        for (int bb = 0; bb < 32; ++bb) { S += p[bb * 256 + c]; Q += p[bb * 256 + 128 + c]; }
        double m = S * (1.0 / 4096.0);
        double var = Q * (1.0 / 4096.0) - m * m;
        double a = (double)g[c] / sqrt(var + 1e-5);
        stA[c] = (float)a;
        stB[c] = (float)((double)e[c] - m * a);
    }
}

// ---------------------------------------------------------------------------
// Kernel 3: dual-job GEMM (CIN=128), 8 rows/block (grid 512 x jobs).
// Round-10 mapping: thread o owns output col o (256-thread block), acc[8].
// ---------------------------------------------------------------------------
__global__ __launch_bounds__(256) void gemm2_kernel(
    const float* __restrict__ Aa, const double* __restrict__ pa,
    const float* __restrict__ ga, const float* __restrict__ ea,
    const float* __restrict__ Wa, const float* __restrict__ ba, float* __restrict__ outa,
    const float* __restrict__ Ab, const double* __restrict__ pb,
    const float* __restrict__ gb, const float* __restrict__ eb,
    const float* __restrict__ Wb, const float* __restrict__ bb, float* __restrict__ outb)
{
    const int job = blockIdx.y;
    const float* A = job ? Ab : Aa;  const double* p = job ? pb : pa;
    const float* g = job ? gb : ga;  const float* e = job ? eb : ea;
    const float* W = job ? Wb : Wa;  const float* bias = job ? bb : ba;
    float* out = job ? outb : outa;

    __shared__ float stA[128], stB[128];
    __shared__ float As[8 * 128];
    const int o = threadIdx.x;
    const int r0 = blockIdx.x * 8;

    compute_st(p, g, e, stA, stB, o, 256);
    __syncthreads();

    for (int t = o; t < 8 * 128; t += 256) {
        int r = t >> 7, c = t & 127;
        As[t] = fmaxf(fmaf(stA[c], A[(r0 + r) * 128 + c], stB[c]), 0.0f);
    }
    __syncthreads();

    float acc[8];
    const float bz = bias[o];
#pragma unroll
    for (int r = 0; r < 8; ++r) acc[r] = bz;

    for (int c = 0; c < 128; c += 4) {
        float w0 = W[(c + 0) * 256 + o];
        float w1 = W[(c + 1) * 256 + o];
        float w2 = W[(c + 2) * 256 + o];
        float w3 = W[(c + 3) * 256 + o];
#pragma unroll
        for (int r = 0; r < 8; ++r) {
            const float4 av = *(const float4*)&As[r * 128 + c];
            acc[r] += av.x * w0 + av.y * w1 + av.z * w2 + av.w * w3;
        }
    }
#pragma unroll
    for (int r = 0; r < 8; ++r)
        out[(r0 + r) * 256 + o] = acc[r];
}

// ---------------------------------------------------------------------------
// Kernel 4: conv-layer apply, 1 row per 128-thread block, up to 2 jobs via
// blockIdx.y. nd (float4) / idx uniform scalar loads; gather loop unrolled
// x4 for 4 outstanding gathers (fmax order identical -> bit-exact).
// ---------------------------------------------------------------------------
__global__ __launch_bounds__(128) void layer_kernel(
    const float4* __restrict__ nd, const int* __restrict__ idxbuf,
    const float* dir0, const float* fo0, float* out0, int K0,
    const float* dir1, const float* fo1, float* out1, int K1)
{
    const int job = blockIdx.y;
    const float* dirs = job ? dir1 : dir0;
    const float* fo = job ? fo1 : fo0;
    float* out = job ? out1 : out0;
    const int K = job ? K1 : K0;

    const int d = threadIdx.x;
    const int row = blockIdx.x;

    float dx = dirs[d], dy = dirs[128 + d], dz = dirs[256 + d];
    float di = 1.0f / fmaxf(sqrtf((dx * dx + dy * dy) + dz * dz), 1e-12f);
    dx *= di; dy *= di; dz *= di;

    const float4* ns = nd + (size_t)row * 100;
    const int* ib = idxbuf + (size_t)row * 100;

    float acc = -1e30f;
    int k = 0;
    for (; k + 4 <= K; k += 4) {
        float4 v0 = ns[k], v1 = ns[k + 1], v2 = ns[k + 2], v3 = ns[k + 3];
        int i0 = ib[k], i1 = ib[k + 1], i2 = ib[k + 2], i3 = ib[k + 3];
        float f0 = fo[i0 * 256 + 128 + d];
        float f1 = fo[i1 * 256 + 128 + d];
        float f2 = fo[i2 * 256 + 128 + d];
        float f3 = fo[i3 * 256 + 128 + d];
        float t0 = fmaxf((v0.x * dx + v0.y * dy) + v0.z * dz, 0.0f);
        float t1 = fmaxf((v1.x * dx + v1.y * dy) + v1.z * dz, 0.0f);
        float t2 = fmaxf((v2.x * dx + v2.y * dy) + v2.z * dz, 0.0f);
        float t3 = fmaxf((v3.x * dx + v3.y * dy) + v3.z * dz, 0.0f);
        acc = fmaxf(acc, t0 * f0);
        acc = fmaxf(acc, t1 * f1);
        acc = fmaxf(acc, t2 * f2);
        acc = fmaxf(acc, t3 * f3);
    }
    for (; k < K; ++k) {
        float4 v = ns[k];
        int ix = ib[k];
        float th = fmaxf((v.x * dx + v.y * dy) + v.z * dz, 0.0f);
        acc = fmaxf(acc, th * fo[ix * 256 + 128 + d]);
    }
    out[row * 128 + d] = fo[row * 256 + d] + acc;
}

// ---------------------------------------------------------------------------
// Kernel 5: final GEMM (CIN=384), 8 rows/block (grid 512), round-10 mapping,
// bn_relu fused into staging, final relu, fp32 out.
// ---------------------------------------------------------------------------
__global__ __launch_bounds__(256) void gemmf_kernel(
    const float* __restrict__ A0t, const double* __restrict__ p0,
    const float* __restrict__ g0, const float* __restrict__ e0,
    const float* __restrict__ A1t, const double* __restrict__ p1,
    const float* __restrict__ g1, const float* __restrict__ e1,
    const float* __restrict__ A2t, const double* __restrict__ p2,
    const float* __restrict__ g2, const float* __restrict__ e2,
    const float* __restrict__ W, const float* __restrict__ bias, float* __restrict__ out)
{
    __shared__ float stA[384], stB[384];
    __shared__ float As[8 * 384];
    const int o = threadIdx.x;
    const int r0 = blockIdx.x * 8;

    compute_st(p0, g0, e0, stA,       stB,       o, 256);
    compute_st(p1, g1, e1, stA + 128, stB + 128, o, 256);
    compute_st(p2, g2, e2, stA + 256, stB + 256, o, 256);
    __syncthreads();

    for (int t = o; t < 8 * 384; t += 256) {
        int r = t / 384, c = t - r * 384;
        int seg = c >> 7, cc = c & 127;
        const float* A = (seg == 0) ? A0t : (seg == 1) ? A1t : A2t;
        As[t] = fmaxf(fmaf(stA[c], A[(r0 + r) * 128 + cc], stB[c]), 0.0f);
    }
    __syncthreads();

    float acc[8];
    const float bz = bias[o];
#pragma unroll
    for (int r = 0; r < 8; ++r) acc[r] = bz;

    for (int c = 0; c < 384; c += 4) {
        float w0 = W[(c + 0) * 256 + o];
        float w1 = W[(c + 1) * 256 + o];
        float w2 = W[(c + 2) * 256 + o];
        float w3 = W[(c + 3) * 256 + o];
#pragma unroll
        for (int r = 0; r < 8; ++r) {
            const float4 av = *(const float4*)&As[r * 384 + c];
            acc[r] += av.x * w0 + av.y * w1 + av.z * w2 + av.w * w3;
        }
    }
#pragma unroll
    for (int r = 0; r < 8; ++r)
        out[(r0 + r) * 256 + o] = fmaxf(acc[r], 0.0f);
}

// ---------------------------------------------------------------------------
extern "C" void kernel_launch(void* const* d_in, const int* in_sizes, int n_in,
                              void* d_out, int out_size, void* d_ws, size_t ws_size,
                              hipStream_t stream)
{
    (void)in_sizes; (void)n_in; (void)out_size; (void)ws_size;

    const float* verts   = (const float*)d_in[0];
    const float* dirs_l  = (const float*)d_in[1];
    const float* dirs_m0 = (const float*)d_in[2];
    const float* W_m1    = (const float*)d_in[3];
    const float* b_m1    = (const float*)d_in[4];
    const float* dirs_m1 = (const float*)d_in[5];
    const float* dirs_g0 = (const float*)d_in[6];
    const float* W_g1    = (const float*)d_in[7];
    const float* b_g1    = (const float*)d_in[8];
    const float* dirs_g1 = (const float*)d_in[9];
    const float* W_g2    = (const float*)d_in[10];
    const float* b_g2    = (const float*)d_in[11];
    const float* dirs_g2 = (const float*)d_in[12];
    const float* g_l  = (const float*)d_in[13]; const float* be_l  = (const float*)d_in[14];
    const float* g_m0 = (const float*)d_in[15]; const float* be_m0 = (const float*)d_in[16];
    const float* g_m1 = (const float*)d_in[17]; const float* be_m1 = (const float*)d_in[18];
    const float* g_g0 = (const float*)d_in[19]; const float* be_g0 = (const float*)d_in[20];
    const float* g_g1 = (const float*)d_in[21]; const float* be_g1 = (const float*)d_in[22];
    const float* g_g2 = (const float*)d_in[23]; const float* be_g2 = (const float*)d_in[24];
    const float* W_down = (const float*)d_in[25];
    const float* b_down = (const float*)d_in[26];

    char* ws = (char*)d_ws;
    const size_t MB = 1 << 20;
    int*    idx100 = (int*)   (ws + 0);               // 1.64 MB
    double* p_l    = (double*)(ws + 0x1A0000);        // 6 x 64 KB fp64 partials
    double* p_m0   = p_l  + 8192;
    double* p_m1   = p_m0 + 8192;
    double* p_g0   = p_m1 + 8192;
    double* p_g1   = p_g0 + 8192;
    double* p_g2   = p_g1 + 8192;
    float4* nd100  = (float4*)(ws + 2 * MB);          // 6.55 MB (stride-4)
    float* raw_l  = (float*)(ws +  9 * MB);           // 2 MB each
    float* raw_m0 = (float*)(ws + 11 * MB);
    float* raw_g0 = (float*)(ws + 13 * MB);
    float* raw_m1 = (float*)(ws + 15 * MB);
    float* raw_g1 = (float*)(ws + 17 * MB);
    float* raw_g2 = (float*)(ws + 19 * MB);
    float* fo_m   = (float*)(ws + 21 * MB);           // 4 MB each
    float* fo_g   = (float*)(ws + 25 * MB);
    float* fo_g2  = (float*)(ws + 29 * MB);

    // L1. KNN + nd + fused surface convs
    knnsurf_kernel<<<1024, 256, 0, stream>>>(verts, idx100, nd100,
                                             dirs_l, dirs_m0, dirs_g0,
                                             raw_l, raw_m0, raw_g0);
    // L2. BN partials for l, m0, g0
    bnsum_kernel<<<96, 256, 0, stream>>>(raw_l, p_l, raw_m0, p_m0, raw_g0, p_g0);
    // L3. fo_m = bn_relu(raw_m0) @ W_m1 ; fo_g = bn_relu(raw_g0) @ W_g1
    gemm2_kernel<<<dim3(512, 2), 256, 0, stream>>>(
        raw_m0, p_m0, g_m0, be_m0, W_m1, b_m1, fo_m,
        raw_g0, p_g0, g_g0, be_g0, W_g1, b_g1, fo_g);
    // L4. conv-layer apply (m1: K=20, g1: K=100)
    layer_kernel<<<dim3(4096, 2), 128, 0, stream>>>(nd100, idx100,
                                                    dirs_m1, fo_m, raw_m1, 20,
                                                    dirs_g1, fo_g, raw_g1, 100);
    // L5. BN partials for m1, g1
    bnsum_kernel<<<64, 256, 0, stream>>>(raw_m1, p_m1, raw_g1, p_g1, raw_g1, p_g1);
    // L6. fo_g2 = bn_relu(raw_g1) @ W_g2
    gemm2_kernel<<<dim3(512, 1), 256, 0, stream>>>(
        raw_g1, p_g1, g_g1, be_g1, W_g2, b_g2, fo_g2,
        raw_g1, p_g1, g_g1, be_g1, W_g2, b_g2, fo_g2);
    // L7. conv-layer apply (g2: K=100)
    layer_kernel<<<dim3(4096, 1), 128, 0, stream>>>(nd100, idx100,
                                                    dirs_g2, fo_g2, raw_g2, 100,
                                                    dirs_g2, fo_g2, raw_g2, 100);
    // L8. BN partials for g2
    bnsum_kernel<<<32, 256, 0, stream>>>(raw_g2, p_g2, raw_g2, p_g2, raw_g2, p_g2);
    // L9. final: relu(concat(bn_relu each) @ W_down + b_down) -> fp32 out
    gemmf_kernel<<<512, 256, 0, stream>>>(raw_l, p_l, g_l, be_l,
                                          raw_m1, p_m1, g_m1, be_m1,
                                          raw_g2, p_g2, g_g2, be_g2,
                                          W_down, b_down, (float*)d_out);
}